// Round 14
// baseline (182.602 us; speedup 1.0000x reference)
//
#include <hip/hip_runtime.h>
#include <hip/hip_bf16.h>
#include <hip/hip_fp16.h>

using bf16 = __hip_bfloat16;
typedef __attribute__((ext_vector_type(8))) short short8;
typedef __attribute__((ext_vector_type(4))) float f32x4;

static constexpr int Bb = 2, Ss = 1024, Dd = 1024, Ee = 64, Nn = 16;

struct Params {
    const float *X, *posW, *posB, *pbias, *spos, *lsc, *qW, *kW, *vW, *gates, *rwp, *lnw, *lnb;
    bf16 *QKV, *Vt, *Aav;
    __half *wh;
    float *qk0, *qk1, *cb0, *cb1, *out;
};

__device__ __forceinline__ unsigned short f2bfr(float f) {
    __hip_bfloat16 h = __float2bfloat16(f);
    return *reinterpret_cast<unsigned short*>(&h);
}
__device__ __forceinline__ unsigned pk2(float a, float b) {
    return ((unsigned)f2bfr(b) << 16) | (unsigned)f2bfr(a);
}
__device__ __forceinline__ int swz(int r) { return (r ^ (r >> 3)) & 7; }

#define GL_LDS(gp, lp) __builtin_amdgcn_global_load_lds( \
    (const __attribute__((address_space(1))) void*)(gp), \
    (__attribute__((address_space(3))) void*)(lp), 16, 0, 0)

// ---------- 64x128 MFMA GEMM tile, BK=64, XOR-swizzled (R7-proven; qk/AV, bf16 src) ----------
__device__ __forceinline__ void do_gemm64(
    const bf16* __restrict__ Ab, const bf16* __restrict__ Bw, float* __restrict__ C,
    int Nc, int m0, int n0, int kBeg, int kEnd, float scale, char* sm)
{
    short* lA = (short*)sm;            // 8 KB
    short* lB = (short*)(sm + 8192);   // 16 KB
    int tid = threadIdx.x, wid = tid >> 6, lane = tid & 63;
    int wn = wid * 32, r16 = lane & 15, quad = lane >> 4;

    f32x4 acc[4][2];
    #pragma unroll
    for (int i = 0; i < 4; ++i)
        #pragma unroll
        for (int j = 0; j < 2; ++j)
            #pragma unroll
            for (int c = 0; c < 4; ++c) acc[i][j][c] = 0.f;

    const short* Ag = (const short*)Ab;
    const short* Bg = (const short*)Bw;

    int arow[2], akg[2], brow[4], bkg[4];
    #pragma unroll
    for (int j = 0; j < 2; ++j) {
        int c = tid + j*256; arow[j] = c >> 3; akg[j] = (c & 7) ^ (arow[j] & 7);
    }
    #pragma unroll
    for (int j = 0; j < 4; ++j) {
        int c = tid + j*256; brow[j] = c >> 3; bkg[j] = (c & 7) ^ (brow[j] & 7);
    }

    for (int k0 = kBeg; k0 < kEnd; k0 += 64) {
        __syncthreads();
        #pragma unroll
        for (int j = 0; j < 2; ++j)
            GL_LDS(Ag + (long)(m0 + arow[j])*1024 + k0 + akg[j]*8, lA + (tid + j*256)*8);
        #pragma unroll
        for (int j = 0; j < 4; ++j)
            GL_LDS(Bg + (long)(n0 + brow[j])*1024 + k0 + bkg[j]*8, lB + (tid + j*256)*8);
        __syncthreads();

        #pragma unroll
        for (int kk = 0; kk < 2; ++kk) {
            int kc = kk*4 + quad;
            short8 af[4], bfv[2];
            #pragma unroll
            for (int i = 0; i < 4; ++i) {
                int r = i*16 + r16;
                af[i] = *(const short8*)(lA + r*64 + (kc ^ (r & 7))*8);
            }
            #pragma unroll
            for (int j = 0; j < 2; ++j) {
                int r = wn + j*16 + r16;
                bfv[j] = *(const short8*)(lB + r*64 + (kc ^ (r & 7))*8);
            }
            #pragma unroll
            for (int i = 0; i < 4; ++i)
                #pragma unroll
                for (int j = 0; j < 2; ++j)
                    acc[i][j] = __builtin_amdgcn_mfma_f32_16x16x32_bf16(af[i], bfv[j], acc[i][j], 0, 0, 0);
        }
    }

    #pragma unroll
    for (int i = 0; i < 4; ++i)
        #pragma unroll
        for (int j = 0; j < 2; ++j)
            #pragma unroll
            for (int rr = 0; rr < 4; ++rr)
                C[(long)(m0 + i*16 + quad*4 + rr)*Nc + n0 + wn + j*16 + r16] =
                    acc[i][j][rr] * scale;
}

// ---------- 128x128 MFMA GEMM, f32 sources staged+converted in-kernel ----------
// A = X f32 [2048][1024]; B = W f32 [1024 k][1024 n] consumed NON-transposed:
// the f32->bf16 pack transposes on the way into LDS (pairs along k -> one b32).
// swz(r) keeps both scatter-writes and MFMA reads <=2-way on banks.
// OUT_MODE 1: bf16 row-major (Q,K). 2: bf16 transposed -> Vt[b][D][S] (V).
template<int OUT_MODE>
__device__ __forceinline__ void do_gemm128f(
    const float* __restrict__ Af, const float* __restrict__ Wf, void* __restrict__ Cv,
    int Nc, int m0, int n0, char* sm)
{
    short* lA = (short*)sm;             // 128*64*2 = 16 KB
    short* lB = (short*)(sm + 16384);   // 16 KB
    int tid = threadIdx.x, wid = tid >> 6, lane = tid & 63;
    int wm = (wid >> 1) * 64, wnn = (wid & 1) * 64;
    int r16 = lane & 15, quad = lane >> 4;

    f32x4 acc[4][4];
    #pragma unroll
    for (int i = 0; i < 4; ++i)
        #pragma unroll
        for (int j = 0; j < 4; ++j)
            #pragma unroll
            for (int c = 0; c < 4; ++c) acc[i][j][c] = 0.f;

    int am = tid >> 1, ak = (tid & 1) * 32;           // A: 128 rows x 64 k
    int brp = tid >> 3, bc = (tid & 7) * 16;          // B: 32 k-row-pairs x 128 n
    int bkch = brp >> 2, bkoff = (2*brp) & 7;

    for (int k0 = 0; k0 < 1024; k0 += 64) {
        __syncthreads();
        // ---- A stage: X f32 -> bf16, same-layout ----
        #pragma unroll
        for (int it = 0; it < 8; ++it) {
            int k = ak + it*4;
            float4 v = *(const float4*)(Af + (long)(m0 + am)*1024 + k0 + k);
            int addr = am*64 + (((k >> 3) ^ swz(am)) * 8) + (k & 7);
            *(unsigned*)(lA + addr)     = pk2(v.x, v.y);
            *(unsigned*)(lA + addr + 2) = pk2(v.z, v.w);
        }
        // ---- B stage: W f32 rows (k-major) -> transposed bf16 [n][k] ----
        #pragma unroll
        for (int it = 0; it < 4; ++it) {
            int c = bc + it*4;
            const float* w0 = Wf + (long)(k0 + 2*brp)*1024 + n0 + c;
            float4 r0 = *(const float4*)w0;
            float4 r1 = *(const float4*)(w0 + 1024);
            float a0[4] = {r0.x, r0.y, r0.z, r0.w};
            float a1[4] = {r1.x, r1.y, r1.z, r1.w};
            #pragma unroll
            for (int i = 0; i < 4; ++i) {
                int n = c + i;
                int addr = n*64 + ((bkch ^ swz(n)) * 8) + bkoff;
                *(unsigned*)(lB + addr) = pk2(a0[i], a1[i]);
            }
        }
        __syncthreads();

        #pragma unroll
        for (int kk = 0; kk < 2; ++kk) {
            int kc = kk*4 + quad;
            short8 af[4], bfv[4];
            #pragma unroll
            for (int i = 0; i < 4; ++i) {
                int r = wm + i*16 + r16;
                af[i] = *(const short8*)(lA + r*64 + (kc ^ swz(r))*8);
            }
            #pragma unroll
            for (int j = 0; j < 4; ++j) {
                int r = wnn + j*16 + r16;
                bfv[j] = *(const short8*)(lB + r*64 + (kc ^ swz(r))*8);
            }
            #pragma unroll
            for (int i = 0; i < 4; ++i)
                #pragma unroll
                for (int j = 0; j < 4; ++j)
                    acc[i][j] = __builtin_amdgcn_mfma_f32_16x16x32_bf16(af[i], bfv[j], acc[i][j], 0, 0, 0);
        }
    }

    if (OUT_MODE == 1) {
        bf16* C = (bf16*)Cv;
        #pragma unroll
        for (int i = 0; i < 4; ++i)
            #pragma unroll
            for (int j = 0; j < 4; ++j)
                #pragma unroll
                for (int rr = 0; rr < 4; ++rr)
                    C[(long)(m0 + wm + i*16 + quad*4 + rr)*Nc + n0 + wnn + j*16 + r16] =
                        __float2bfloat16(acc[i][j][rr]);
    } else {
        __syncthreads();
        bf16 (*lt)[132] = (bf16(*)[132])sm;   // 33792 B
        #pragma unroll
        for (int i = 0; i < 4; ++i)
            #pragma unroll
            for (int j = 0; j < 4; ++j)
                #pragma unroll
                for (int rr = 0; rr < 4; ++rr)
                    lt[wnn + j*16 + r16][wm + i*16 + quad*4 + rr] =
                        __float2bfloat16(acc[i][j][rr]);
        __syncthreads();
        bf16* Vb = (bf16*)Cv + (long)(m0 >> 10) * Dd * Ss;
        int s0 = m0 & (Ss - 1);
        int colBase = wid * 32 + (lane >> 4);
        int idx = (lane & 15) * 8;
        #pragma unroll
        for (int it = 0; it < 8; ++it) {
            int col = colBase + it * 4;
            ushort4 v0 = *(const ushort4*)&lt[col][idx];
            ushort4 v1 = *(const ushort4*)&lt[col][idx + 4];
            *(ushort4*)(Vb + (long)(n0 + col)*Ss + s0 + idx)     = v0;
            *(ushort4*)(Vb + (long)(n0 + col)*Ss + s0 + idx + 4) = v1;
        }
    }
}

// ---------- pos GEMM from f32 sources + tanh/bias + splat influence -> wh ----------
__device__ __forceinline__ void do_pos32(const Params& p, int m0, char* sm)
{
    short* lA = (short*)sm;                          // 64*64*2 = 8 KB
    short* lB = (short*)(sm + 8192);                 // 8 KB
    float (*P)[65]  = (float(*)[65])(sm + 16384);    // 16640 B
    float (*sp)[65] = (float(*)[65])(sm + 16384 + 16640); // 4160 B -> 37184 total

    int tid = threadIdx.x, wid = tid >> 6, lane = tid & 63;
    int r16 = lane & 15, quad = lane >> 4;

    for (int idx = tid; idx < 16*64; idx += 256)
        sp[idx >> 6][idx & 63] = p.spos[idx];

    f32x4 acc[4];
    #pragma unroll
    for (int j = 0; j < 4; ++j)
        #pragma unroll
        for (int c = 0; c < 4; ++c) acc[j][c] = 0.f;

    int am = tid >> 2, ak = (tid & 3) * 16;          // A: 64 rows x 64 k
    int brp = tid >> 3, bc = (tid & 7) * 8;          // B: 32 k-row-pairs x 64 n
    int bkch = brp >> 2, bkoff = (2*brp) & 7;

    for (int k0 = 0; k0 < 1024; k0 += 64) {
        __syncthreads();
        #pragma unroll
        for (int it = 0; it < 4; ++it) {
            int k = ak + it*4;
            float4 v = *(const float4*)(p.X + (long)(m0 + am)*1024 + k0 + k);
            int addr = am*64 + (((k >> 3) ^ swz(am)) * 8) + (k & 7);
            *(unsigned*)(lA + addr)     = pk2(v.x, v.y);
            *(unsigned*)(lA + addr + 2) = pk2(v.z, v.w);
        }
        #pragma unroll
        for (int it = 0; it < 2; ++it) {
            int c = bc + it*4;
            const float* w0 = p.posW + (long)(k0 + 2*brp)*Ee + c;
            float4 r0 = *(const float4*)w0;
            float4 r1 = *(const float4*)(w0 + Ee);
            float a0[4] = {r0.x, r0.y, r0.z, r0.w};
            float a1[4] = {r1.x, r1.y, r1.z, r1.w};
            #pragma unroll
            for (int i = 0; i < 4; ++i) {
                int n = c + i;
                int addr = n*64 + ((bkch ^ swz(n)) * 8) + bkoff;
                *(unsigned*)(lB + addr) = pk2(a0[i], a1[i]);
            }
        }
        __syncthreads();

        #pragma unroll
        for (int kk = 0; kk < 2; ++kk) {
            int kc = kk*4 + quad;
            int ra = wid*16 + r16;
            short8 af = *(const short8*)(lA + ra*64 + (kc ^ swz(ra))*8);
            #pragma unroll
            for (int j = 0; j < 4; ++j) {
                int r = j*16 + r16;
                short8 bfv = *(const short8*)(lB + r*64 + (kc ^ swz(r))*8);
                acc[j] = __builtin_amdgcn_mfma_f32_16x16x32_bf16(af, bfv, acc[j], 0, 0, 0);
            }
        }
    }

    #pragma unroll
    for (int j = 0; j < 4; ++j)
        #pragma unroll
        for (int rr = 0; rr < 4; ++rr) {
            int rl  = wid*16 + quad*4 + rr;
            int col = j*16 + r16;
            int srow = (m0 + rl) & (Ss - 1);
            P[rl][col] = tanhf(acc[j][rr] + p.posB[col]) + p.pbias[srow*Ee + col];
        }
    __syncthreads();

    int n  = tid & 15;
    int rb = (tid >> 4) * 4;
    float sc = __expf(p.lsc[n]);
    sc = fminf(fmaxf(sc, 0.3f), 2.0f);
    float inv2 = -0.5f / (sc * sc);
    #pragma unroll
    for (int rr = 0; rr < 4; ++rr) {
        int row = rb + rr;
        float d2 = 0.f;
        #pragma unroll 16
        for (int e = 0; e < 64; ++e) {
            float df = P[row][e] - sp[n][e];
            d2 += df * df;
        }
        float infl = fmaxf(__expf(d2 * inv2), 0.01f);
        p.wh[(long)(m0 + row)*Nn + n] = __float2half(infl);
    }
}

// ========== K1: QKV GEMM from f32 (384 jobs; V transposed) + pos (32 jobs) ==========
__global__ __launch_bounds__(256) void k_qkv_pos(Params p)
{
    __shared__ __align__(16) char sm[37184];   // max(pos 37184, gemm 32K, V-lt 33792)
    int job = blockIdx.x;
    if (job < 384) {
        int z = job >> 7, t = job & 127;
        int bm = t >> 3, bn = t & 7;
        const float* Wf = (z == 0) ? p.qW : (z == 1) ? p.kW : p.vW;
        if (z < 2)
            do_gemm128f<1>(p.X, Wf, p.QKV + (long)z*2048*1024, Dd, bm*128, bn*128, sm);
        else
            do_gemm128f<2>(p.X, Wf, p.Vt, Dd, bm*128, bn*128, sm);
    } else {
        do_pos32(p, (job - 384)*64, sm);
    }
}

// ========== K2: qk split-K (288 jobs) ==========
__global__ __launch_bounds__(256) void k_qkt(Params p)
{
    __shared__ __align__(16) char sm[24576];
    int job = blockIdx.x;
    int pairIdx = job >> 1, h = job & 1;
    int b = pairIdx / 72, t = pairIdx % 72;
    int acc = 0, bm = 0, bn = 0;
    #pragma unroll
    for (int u = 0; u < 16; ++u) {
        int c = (u >> 1) + 1;
        if (t < acc + c) { bm = u; bn = t - acc; break; }
        acc += c;
    }
    const bf16* Qb = p.QKV + (long)b*Ss*Dd;
    const bf16* Kb = p.QKV + (long)2048*1024 + (long)b*Ss*Dd;
    float* dst = (h ? p.qk1 : p.qk0) + (long)b*Ss*Ss;
    do_gemm64(Qb, Kb, dst, Ss, bm*64, bn*128, h*512, h*512 + 512, 0.03125f, sm);
}

// ========== K3: softmax + gated average; qk row cached in 16 regs/lane ==========
__global__ __launch_bounds__(256) void k_softmax(Params p)
{
    __shared__ __align__(16) char sm[36864 + 256];
    __half2 (*wt)[9] = (__half2(*)[9])sm;
    float (*wi4)[16] = (float(*)[16])(sm + 36864);

    int base = blockIdx.x * 4, b = blockIdx.y;
    int tid = threadIdx.x, wid = tid >> 6, lane = tid & 63;
    int imax = base + 3;

    const __half*  whb  = p.wh + (long)b*Ss*Nn;
    const __half2* whb2 = (const __half2*)whb;

    for (int j = tid; j <= imax; j += 256) {
        #pragma unroll
        for (int h = 0; h < 8; ++h)
            wt[j][h] = whb2[j*8 + h];
    }
    if (tid < 64) wi4[tid >> 4][tid & 15] =
        __half2float(whb[(long)(base + (tid >> 4))*16 + (tid & 15)]);
    __syncthreads();

    int i = base + wid;
    const float* q0 = p.qk0 + ((long)b*Ss + i)*Ss;
    const float* q1 = p.qk1 + ((long)b*Ss + i)*Ss;
    bf16* arow      = p.Aav + ((long)b*Ss + i)*Ss;

    float wiR[16], l[16], qv[16];
    #pragma unroll
    for (int n = 0; n < 16; ++n) { wiR[n] = wi4[wid][n]; l[n] = 0.f; }

    #pragma unroll
    for (int t = 0; t < 16; ++t) {
        int j = lane + 64*t;
        if (j <= i) {
            float q = q0[j] + q1[j];
            qv[t] = q;
            #pragma unroll
            for (int h = 0; h < 8; ++h) {
                float2 f = __half22float2(wt[j][h]);
                l[2*h]     += __expf(wiR[2*h]     * f.x * q);
                l[2*h + 1] += __expf(wiR[2*h + 1] * f.y * q);
            }
        }
    }
    #pragma unroll
    for (int n = 0; n < 16; ++n)
        #pragma unroll
        for (int off = 32; off > 0; off >>= 1)
            l[n] += __shfl_xor(l[n], off);

    float coef[16];
    #pragma unroll
    for (int n = 0; n < 16; ++n) {
        float g  = p.gates[n];
        float sg = 1.f / (1.f + __expf(-g));
        coef[n]  = sg / (16.f * l[n]);
    }

    #pragma unroll
    for (int t = 0; t < 16; ++t) {
        int j = lane + 64*t;
        float a = 0.f;
        if (j <= i) {
            float q = qv[t];
            #pragma unroll
            for (int h = 0; h < 8; ++h) {
                float2 f = __half22float2(wt[j][h]);
                a += coef[2*h]     * __expf(wiR[2*h]     * f.x * q);
                a += coef[2*h + 1] * __expf(wiR[2*h + 1] * f.y * q);
            }
        }
        arow[j] = __float2bfloat16(a);
    }
}

// ========== K4: AV GEMM split-K (384 jobs) ==========
__global__ __launch_bounds__(256) void k_av(Params p)
{
    __shared__ __align__(16) char sm[24576];
    int job = blockIdx.x;
    int b, bm, bn, kBeg, kEnd;
    if (job < 256) {
        b = job >> 7; int t = job & 127; bm = t >> 3; bn = t & 7;
        kBeg = 0; kEnd = bm*64 + 64; if (kEnd > 512) kEnd = 512;
    } else {
        int j = job - 256;
        b = j >> 6; int t = j & 63; bm = 8 + (t >> 3); bn = t & 7;
        kBeg = 512; kEnd = bm*64 + 64;
    }
    const bf16* Ab = p.Aav + (long)b*Ss*Ss;
    const bf16* Bw = p.Vt + (long)b*Dd*Ss;
    float* dst = (job < 256 ? p.cb0 : p.cb1) + (long)b*Ss*Dd;
    do_gemm64(Ab, Bw, dst, Dd, bm*64, bn*128, kBeg, kEnd, 1.f, sm);
}

// ========== K5: residual + LayerNorm ==========
__global__ __launch_bounds__(256) void k_epilogue(Params p)
{
    __shared__ float rs[4], rq[4];
    long row = blockIdx.x;
    int tid = threadIdx.x, wid = tid >> 6, lane = tid & 63;
    float rw = 1.f / (1.f + __expf(-p.rwp[0]));

    float4 c0 = ((const float4*)(p.cb0 + row*Dd))[tid];
    int s = (int)(row & (Ss - 1));
    float4 c1 = make_float4(0.f, 0.f, 0.f, 0.f);
    if (s >= 512) c1 = ((const float4*)(p.cb1 + row*Dd))[tid];
    float4 xv = ((const float4*)(p.X + row*Dd))[tid];

    float o[4];
    o[0] = rw * xv.x + (1.f - rw) * (c0.x + c1.x);
    o[1] = rw * xv.y + (1.f - rw) * (c0.y + c1.y);
    o[2] = rw * xv.z + (1.f - rw) * (c0.z + c1.z);
    o[3] = rw * xv.w + (1.f - rw) * (c0.w + c1.w);

    float sm1 = o[0] + o[1] + o[2] + o[3];
    float sq  = o[0]*o[0] + o[1]*o[1] + o[2]*o[2] + o[3]*o[3];
    #pragma unroll
    for (int off = 32; off > 0; off >>= 1) { sm1 += __shfl_xor(sm1, off); sq += __shfl_xor(sq, off); }
    if (lane == 0) { rs[wid] = sm1; rq[wid] = sq; }
    __syncthreads();
    sm1 = rs[0] + rs[1] + rs[2] + rs[3];
    sq  = rq[0] + rq[1] + rq[2] + rq[3];
    float mu  = sm1 * (1.f/1024.f);
    float var = sq * (1.f/1024.f) - mu*mu;
    float inv = rsqrtf(var + 1e-5f);

    float4 lw = ((const float4*)p.lnw)[tid];
    float4 lb = ((const float4*)p.lnb)[tid];
    float4 y;
    y.x = (o[0] - mu)*inv*lw.x + lb.x;
    y.y = (o[1] - mu)*inv*lw.y + lb.y;
    y.z = (o[2] - mu)*inv*lw.z + lb.z;
    y.w = (o[3] - mu)*inv*lw.w + lb.w;
    ((float4*)(p.out + row*Dd))[tid] = y;
}

extern "C" void kernel_launch(void* const* d_in, const int* in_sizes, int n_in,
                              void* d_out, int out_size, void* d_ws, size_t ws_size,
                              hipStream_t stream)
{
    Params prm;
    prm.X     = (const float*)d_in[0];
    prm.posW  = (const float*)d_in[1];
    prm.posB  = (const float*)d_in[2];
    prm.pbias = (const float*)d_in[3];
    prm.spos  = (const float*)d_in[4];
    prm.lsc   = (const float*)d_in[5];
    prm.qW    = (const float*)d_in[6];
    prm.kW    = (const float*)d_in[7];
    prm.vW    = (const float*)d_in[8];
    prm.gates = (const float*)d_in[9];
    prm.rwp   = (const float*)d_in[10];
    prm.lnw   = (const float*)d_in[11];
    prm.lnb   = (const float*)d_in[12];

    char* ws = (char*)d_ws;
    size_t off = 0;
    prm.QKV = (bf16*)(ws + off);   off += (size_t)2*2048*1024*2;  // Q,K (V -> Vt)
    prm.Vt  = (bf16*)(ws + off);   off += (size_t)Bb*Dd*Ss*2;
    prm.Aav = (bf16*)(ws + off);   off += (size_t)Bb*Ss*Ss*2;
    prm.wh  = (__half*)(ws + off); off += (size_t)Bb*Ss*Nn*2;
    prm.qk0 = (float*)(ws + off);  off += (size_t)Bb*Ss*Ss*4;
    prm.qk1 = (float*)(ws + off);  off += (size_t)Bb*Ss*Ss*4;
    prm.cb0 = (float*)(ws + off);  off += (size_t)Bb*Ss*Dd*4;
    prm.cb1 = (float*)(ws + off);  off += (size_t)Bb*Ss*Dd*4;
    prm.out = (float*)d_out;
    (void)ws_size;

    k_qkv_pos <<<416,          256, 0, stream>>>(prm);
    k_qkt     <<<288,          256, 0, stream>>>(prm);
    k_softmax <<<dim3(256, 2), 256, 0, stream>>>(prm);
    k_av      <<<384,          256, 0, stream>>>(prm);
    k_epilogue<<<2048,         256, 0, stream>>>(prm);
}

// Round 15
// 164.635 us; speedup vs baseline: 1.1091x; 1.1091x over previous
//
#include <hip/hip_runtime.h>
#include <hip/hip_bf16.h>
#include <hip/hip_fp16.h>

using bf16 = __hip_bfloat16;
typedef __attribute__((ext_vector_type(8))) short short8;
typedef __attribute__((ext_vector_type(4))) float f32x4;

static constexpr int Bb = 2, Ss = 1024, Dd = 1024, Ee = 64, Nn = 16;

struct Params {
    const float *X, *posW, *posB, *pbias, *spos, *lsc, *qW, *kW, *vW, *gates, *rwp, *lnw, *lnb;
    bf16 *Xb, *Wt, *WpT, *QKV, *Vt, *Aav;
    __half *wh;
    float *qk0, *qk1, *cb0, *cb1, *out;
};

__device__ __forceinline__ unsigned short f2bfr(float f) {
    __hip_bfloat16 h = __float2bfloat16(f);
    return *reinterpret_cast<unsigned short*>(&h);
}

#define GL_LDS(gp, lp) __builtin_amdgcn_global_load_lds( \
    (const __attribute__((address_space(1))) void*)(gp), \
    (__attribute__((address_space(3))) void*)(lp), 16, 0, 0)

// ---------- f32 -> bf16 transpose of a 64x64 tile ----------
__device__ __forceinline__ void do_transpose_f2b(
    const float* __restrict__ in, bf16* __restrict__ out,
    int R, int C, int bx, int by, char* sm)
{
    float (*tile)[65] = (float(*)[65])sm;
    int tx = threadIdx.x & 63, ty = threadIdx.x >> 6;
    int r0 = by * 64, c0 = bx * 64;
    #pragma unroll
    for (int i = 0; i < 16; ++i)
        tile[ty + i*4][tx] = in[(long)(r0 + ty + i*4)*C + c0 + tx];
    __syncthreads();
    #pragma unroll
    for (int i = 0; i < 16; ++i)
        out[(long)(c0 + ty + i*4)*R + r0 + tx] = __float2bfloat16(tile[tx][ty + i*4]);
    __syncthreads();
}

// ---------- 64x128 MFMA GEMM tile, BK=64, XOR-swizzled (R7-proven; qk/AV) ----------
__device__ __forceinline__ void do_gemm64(
    const bf16* __restrict__ Ab, const bf16* __restrict__ Bw, float* __restrict__ C,
    int Nc, int m0, int n0, int kBeg, int kEnd, float scale, char* sm)
{
    short* lA = (short*)sm;            // 8 KB
    short* lB = (short*)(sm + 8192);   // 16 KB
    int tid = threadIdx.x, wid = tid >> 6, lane = tid & 63;
    int wn = wid * 32, r16 = lane & 15, quad = lane >> 4;

    f32x4 acc[4][2];
    #pragma unroll
    for (int i = 0; i < 4; ++i)
        #pragma unroll
        for (int j = 0; j < 2; ++j)
            #pragma unroll
            for (int c = 0; c < 4; ++c) acc[i][j][c] = 0.f;

    const short* Ag = (const short*)Ab;
    const short* Bg = (const short*)Bw;

    int arow[2], akg[2], brow[4], bkg[4];
    #pragma unroll
    for (int j = 0; j < 2; ++j) {
        int c = tid + j*256; arow[j] = c >> 3; akg[j] = (c & 7) ^ (arow[j] & 7);
    }
    #pragma unroll
    for (int j = 0; j < 4; ++j) {
        int c = tid + j*256; brow[j] = c >> 3; bkg[j] = (c & 7) ^ (brow[j] & 7);
    }

    for (int k0 = kBeg; k0 < kEnd; k0 += 64) {
        __syncthreads();
        #pragma unroll
        for (int j = 0; j < 2; ++j)
            GL_LDS(Ag + (long)(m0 + arow[j])*1024 + k0 + akg[j]*8, lA + (tid + j*256)*8);
        #pragma unroll
        for (int j = 0; j < 4; ++j)
            GL_LDS(Bg + (long)(n0 + brow[j])*1024 + k0 + bkg[j]*8, lB + (tid + j*256)*8);
        __syncthreads();

        #pragma unroll
        for (int kk = 0; kk < 2; ++kk) {
            int kc = kk*4 + quad;
            short8 af[4], bfv[2];
            #pragma unroll
            for (int i = 0; i < 4; ++i) {
                int r = i*16 + r16;
                af[i] = *(const short8*)(lA + r*64 + (kc ^ (r & 7))*8);
            }
            #pragma unroll
            for (int j = 0; j < 2; ++j) {
                int r = wn + j*16 + r16;
                bfv[j] = *(const short8*)(lB + r*64 + (kc ^ (r & 7))*8);
            }
            #pragma unroll
            for (int i = 0; i < 4; ++i)
                #pragma unroll
                for (int j = 0; j < 2; ++j)
                    acc[i][j] = __builtin_amdgcn_mfma_f32_16x16x32_bf16(af[i], bfv[j], acc[i][j], 0, 0, 0);
        }
    }

    #pragma unroll
    for (int i = 0; i < 4; ++i)
        #pragma unroll
        for (int j = 0; j < 2; ++j)
            #pragma unroll
            for (int rr = 0; rr < 4; ++rr)
                C[(long)(m0 + i*16 + quad*4 + rr)*Nc + n0 + wn + j*16 + r16] =
                    acc[i][j][rr] * scale;
}

// ---------- 128x128 MFMA GEMM tile (m97 structure), BK=64, XOR-swizzled ----------
template<int OUT_MODE>
__device__ __forceinline__ void do_gemm128(
    const bf16* __restrict__ Ab, const bf16* __restrict__ Bw, void* __restrict__ Cv,
    int Nc, int m0, int n0, char* sm)
{
    short* lA = (short*)sm;             // 16 KB
    short* lB = (short*)(sm + 16384);   // 16 KB
    int tid = threadIdx.x, wid = tid >> 6, lane = tid & 63;
    int wm = (wid >> 1) * 64, wnn = (wid & 1) * 64;
    int r16 = lane & 15, quad = lane >> 4;

    f32x4 acc[4][4];
    #pragma unroll
    for (int i = 0; i < 4; ++i)
        #pragma unroll
        for (int j = 0; j < 4; ++j)
            #pragma unroll
            for (int c = 0; c < 4; ++c) acc[i][j][c] = 0.f;

    const short* Ag = (const short*)Ab;
    const short* Bg = (const short*)Bw;

    int rowc[4], kgc[4];
    #pragma unroll
    for (int j = 0; j < 4; ++j) {
        int c = tid + j*256; rowc[j] = c >> 3; kgc[j] = (c & 7) ^ (rowc[j] & 7);
    }

    for (int k0 = 0; k0 < 1024; k0 += 64) {
        __syncthreads();
        #pragma unroll
        for (int j = 0; j < 4; ++j)
            GL_LDS(Ag + (long)(m0 + rowc[j])*1024 + k0 + kgc[j]*8, lA + (tid + j*256)*8);
        #pragma unroll
        for (int j = 0; j < 4; ++j)
            GL_LDS(Bg + (long)(n0 + rowc[j])*1024 + k0 + kgc[j]*8, lB + (tid + j*256)*8);
        __syncthreads();

        #pragma unroll
        for (int kk = 0; kk < 2; ++kk) {
            int kc = kk*4 + quad;
            short8 af[4], bfv[4];
            #pragma unroll
            for (int i = 0; i < 4; ++i) {
                int r = wm + i*16 + r16;
                af[i] = *(const short8*)(lA + r*64 + (kc ^ (r & 7))*8);
            }
            #pragma unroll
            for (int j = 0; j < 4; ++j) {
                int r = wnn + j*16 + r16;
                bfv[j] = *(const short8*)(lB + r*64 + (kc ^ (r & 7))*8);
            }
            #pragma unroll
            for (int i = 0; i < 4; ++i)
                #pragma unroll
                for (int j = 0; j < 4; ++j)
                    acc[i][j] = __builtin_amdgcn_mfma_f32_16x16x32_bf16(af[i], bfv[j], acc[i][j], 0, 0, 0);
        }
    }

    if (OUT_MODE == 1) {
        bf16* C = (bf16*)Cv;
        #pragma unroll
        for (int i = 0; i < 4; ++i)
            #pragma unroll
            for (int j = 0; j < 4; ++j)
                #pragma unroll
                for (int rr = 0; rr < 4; ++rr)
                    C[(long)(m0 + wm + i*16 + quad*4 + rr)*Nc + n0 + wnn + j*16 + r16] =
                        __float2bfloat16(acc[i][j][rr]);
    } else {
        __syncthreads();
        bf16 (*lt)[132] = (bf16(*)[132])sm;   // 33792 B
        #pragma unroll
        for (int i = 0; i < 4; ++i)
            #pragma unroll
            for (int j = 0; j < 4; ++j)
                #pragma unroll
                for (int rr = 0; rr < 4; ++rr)
                    lt[wnn + j*16 + r16][wm + i*16 + quad*4 + rr] =
                        __float2bfloat16(acc[i][j][rr]);
        __syncthreads();
        bf16* Vb = (bf16*)Cv + (long)(m0 >> 10) * Dd * Ss;
        int s0 = m0 & (Ss - 1);
        int colBase = wid * 32 + (lane >> 4);
        int idx = (lane & 15) * 8;
        #pragma unroll
        for (int it = 0; it < 8; ++it) {
            int col = colBase + it * 4;
            ushort4 v0 = *(const ushort4*)&lt[col][idx];
            ushort4 v1 = *(const ushort4*)&lt[col][idx + 4];
            *(ushort4*)(Vb + (long)(n0 + col)*Ss + s0 + idx)     = v0;
            *(ushort4*)(Vb + (long)(n0 + col)*Ss + s0 + idx + 4) = v1;
        }
    }
}

// ---------- pos GEMM (64 rows) + tanh/bias + splat influence -> wh (half) ----------
__device__ __forceinline__ void do_pos(const Params& p, int m0, char* sm)
{
    short* lA = (short*)sm;
    short* lB = (short*)(sm + 4096);
    float (*P)[65]  = (float(*)[65])(sm + 8192);
    float (*sp)[65] = (float(*)[65])(sm + 8192 + 64*65*4);

    int tid = threadIdx.x, wid = tid >> 6, lane = tid & 63;
    int r16 = lane & 15, quad = lane >> 4;

    for (int idx = tid; idx < 16*64; idx += 256)
        sp[idx >> 6][idx & 63] = p.spos[idx];

    f32x4 acc[4];
    #pragma unroll
    for (int j = 0; j < 4; ++j)
        #pragma unroll
        for (int c = 0; c < 4; ++c) acc[j][c] = 0.f;

    int ra = tid >> 2, ka = (tid & 3) * 8;
    const short* Ag = (const short*)p.Xb;
    const short* Bg = (const short*)p.WpT;

    for (int k0 = 0; k0 < Dd; k0 += 32) {
        __syncthreads();
        GL_LDS(Ag + (long)(m0+ra)*1024 + k0 + ka, lA + tid*8);
        GL_LDS(Bg + (long)ra*1024 + k0 + ka,      lB + tid*8);
        __syncthreads();

        short8 af = *(const short8*)(lA + (wid*16 + r16)*32 + quad*8);
        #pragma unroll
        for (int j = 0; j < 4; ++j) {
            short8 bfv = *(const short8*)(lB + (j*16 + r16)*32 + quad*8);
            acc[j] = __builtin_amdgcn_mfma_f32_16x16x32_bf16(af, bfv, acc[j], 0, 0, 0);
        }
    }

    #pragma unroll
    for (int j = 0; j < 4; ++j)
        #pragma unroll
        for (int rr = 0; rr < 4; ++rr) {
            int rl  = wid*16 + quad*4 + rr;
            int col = j*16 + r16;
            int srow = (m0 + rl) & (Ss - 1);
            P[rl][col] = tanhf(acc[j][rr] + p.posB[col]) + p.pbias[srow*Ee + col];
        }
    __syncthreads();

    int n  = tid & 15;
    int rb = (tid >> 4) * 4;
    float sc = __expf(p.lsc[n]);
    sc = fminf(fmaxf(sc, 0.3f), 2.0f);
    float inv2 = -0.5f / (sc * sc);
    #pragma unroll
    for (int rr = 0; rr < 4; ++rr) {
        int row = rb + rr;
        float d2 = 0.f;
        #pragma unroll 16
        for (int e = 0; e < 64; ++e) {
            float df = P[row][e] - sp[n][e];
            d2 += df * df;
        }
        float infl = fmaxf(__expf(d2 * inv2), 0.01f);
        p.wh[(long)(m0 + row)*Nn + n] = __float2half(infl);
    }
}

// ========== K1: weight transposes + posW^T + X cast ==========
__global__ __launch_bounds__(256) void k_prep(Params p)
{
    __shared__ __align__(16) char sm[64*65*4];
    int z = blockIdx.z;
    if (z < 3) {
        const float* w = (z == 0) ? p.qW : (z == 1) ? p.kW : p.vW;
        do_transpose_f2b(w, p.Wt + (long)z*Dd*Dd, Dd, Dd, blockIdx.x, blockIdx.y, sm);
    } else if (blockIdx.x == 0) {
        do_transpose_f2b(p.posW, p.WpT, Dd, Ee, 0, blockIdx.y, sm);
    } else {
        int job = blockIdx.y * 15 + (blockIdx.x - 1);     // 0..239
        const float4* src = (const float4*)p.X;
        ushort4* dst = (ushort4*)p.Xb;
        for (int idx = job*256 + (int)threadIdx.x; idx < Bb*Ss*Dd/4; idx += 240*256) {
            float4 v = src[idx];
            ushort4 y;
            y.x = f2bfr(v.x); y.y = f2bfr(v.y); y.z = f2bfr(v.z); y.w = f2bfr(v.w);
            dst[idx] = y;
        }
    }
}

// ========== K2: QKV GEMM 128x128 (384 jobs; V transposed) + pos (32 jobs) ==========
__global__ __launch_bounds__(256) void k_qkv_pos(Params p)
{
    __shared__ __align__(16) char sm[33792];
    int job = blockIdx.x;
    if (job < 384) {
        int z = job >> 7, t = job & 127;
        int bm = t >> 3, bn = t & 7;
        if (z < 2)
            do_gemm128<1>(p.Xb, p.Wt + (long)z*Dd*Dd, p.QKV + (long)z*2048*1024,
                          Dd, bm*128, bn*128, sm);
        else
            do_gemm128<2>(p.Xb, p.Wt + (long)2*Dd*Dd, p.Vt,
                          Dd, bm*128, bn*128, sm);
    } else {
        do_pos(p, (job - 384)*64, sm);
    }
}

// ========== K3: qk split-K (288 jobs) ==========
__global__ __launch_bounds__(256) void k_qkt(Params p)
{
    __shared__ __align__(16) char sm[24576];
    int job = blockIdx.x;
    int pairIdx = job >> 1, h = job & 1;
    int b = pairIdx / 72, t = pairIdx % 72;
    int acc = 0, bm = 0, bn = 0;
    #pragma unroll
    for (int u = 0; u < 16; ++u) {
        int c = (u >> 1) + 1;
        if (t < acc + c) { bm = u; bn = t - acc; break; }
        acc += c;
    }
    const bf16* Qb = p.QKV + (long)b*Ss*Dd;
    const bf16* Kb = p.QKV + (long)2048*1024 + (long)b*Ss*Dd;
    float* dst = (h ? p.qk1 : p.qk0) + (long)b*Ss*Ss;
    do_gemm64(Qb, Kb, dst, Ss, bm*64, bn*128, h*512, h*512 + 512, 0.03125f, sm);
}

// ========== K4: softmax + gated average, no max-pass (scores bounded ~±8) ==========
__global__ __launch_bounds__(256) void k_softmax(Params p)
{
    __shared__ __align__(16) char sm[36864 + 256];
    __half2 (*wt)[9] = (__half2(*)[9])sm;
    float (*wi4)[16] = (float(*)[16])(sm + 36864);

    int base = blockIdx.x * 4, b = blockIdx.y;
    int tid = threadIdx.x, wid = tid >> 6, lane = tid & 63;
    int imax = base + 3;

    const __half*  whb  = p.wh + (long)b*Ss*Nn;
    const __half2* whb2 = (const __half2*)whb;

    for (int j = tid; j <= imax; j += 256) {
        #pragma unroll
        for (int h = 0; h < 8; ++h)
            wt[j][h] = whb2[j*8 + h];
    }
    if (tid < 64) wi4[tid >> 4][tid & 15] =
        __half2float(whb[(long)(base + (tid >> 4))*16 + (tid & 15)]);
    __syncthreads();

    int i = base + wid;
    const float* q0 = p.qk0 + ((long)b*Ss + i)*Ss;
    const float* q1 = p.qk1 + ((long)b*Ss + i)*Ss;
    bf16* arow      = p.Aav + ((long)b*Ss + i)*Ss;

    float wiR[16], l[16];
    #pragma unroll
    for (int n = 0; n < 16; ++n) { wiR[n] = wi4[wid][n]; l[n] = 0.f; }

    for (int j = lane; j <= i; j += 64) {
        float q = q0[j] + q1[j];
        #pragma unroll
        for (int h = 0; h < 8; ++h) {
            float2 f = __half22float2(wt[j][h]);
            l[2*h]     += __expf(wiR[2*h]     * f.x * q);
            l[2*h + 1] += __expf(wiR[2*h + 1] * f.y * q);
        }
    }
    #pragma unroll
    for (int n = 0; n < 16; ++n)
        #pragma unroll
        for (int off = 32; off > 0; off >>= 1)
            l[n] += __shfl_xor(l[n], off);

    float coef[16];
    #pragma unroll
    for (int n = 0; n < 16; ++n) {
        float g  = p.gates[n];
        float sg = 1.f / (1.f + __expf(-g));
        coef[n]  = sg / (16.f * l[n]);
    }

    for (int j = lane; j < Ss; j += 64) {
        float a = 0.f;
        if (j <= i) {
            float q = q0[j] + q1[j];
            #pragma unroll
            for (int h = 0; h < 8; ++h) {
                float2 f = __half22float2(wt[j][h]);
                a += coef[2*h]     * __expf(wiR[2*h]     * f.x * q);
                a += coef[2*h + 1] * __expf(wiR[2*h + 1] * f.y * q);
            }
        }
        arow[j] = __float2bfloat16(a);
    }
}

// ========== K5: AV GEMM split-K (384 jobs) ==========
__global__ __launch_bounds__(256) void k_av(Params p)
{
    __shared__ __align__(16) char sm[24576];
    int job = blockIdx.x;
    int b, bm, bn, kBeg, kEnd;
    if (job < 256) {
        b = job >> 7; int t = job & 127; bm = t >> 3; bn = t & 7;
        kBeg = 0; kEnd = bm*64 + 64; if (kEnd > 512) kEnd = 512;
    } else {
        int j = job - 256;
        b = j >> 6; int t = j & 63; bm = 8 + (t >> 3); bn = t & 7;
        kBeg = 512; kEnd = bm*64 + 64;
    }
    const bf16* Ab = p.Aav + (long)b*Ss*Ss;
    const bf16* Bw = p.Vt + (long)b*Dd*Ss;
    float* dst = (job < 256 ? p.cb0 : p.cb1) + (long)b*Ss*Dd;
    do_gemm64(Ab, Bw, dst, Dd, bm*64, bn*128, kBeg, kEnd, 1.f, sm);
}

// ========== K6: residual + LayerNorm ==========
__global__ __launch_bounds__(256) void k_epilogue(Params p)
{
    __shared__ float rs[4], rq[4];
    long row = blockIdx.x;
    int tid = threadIdx.x, wid = tid >> 6, lane = tid & 63;
    float rw = 1.f / (1.f + __expf(-p.rwp[0]));

    float4 c0 = ((const float4*)(p.cb0 + row*Dd))[tid];
    int s = (int)(row & (Ss - 1));
    float4 c1 = make_float4(0.f, 0.f, 0.f, 0.f);
    if (s >= 512) c1 = ((const float4*)(p.cb1 + row*Dd))[tid];
    float4 xv = ((const float4*)(p.X + row*Dd))[tid];

    float o[4];
    o[0] = rw * xv.x + (1.f - rw) * (c0.x + c1.x);
    o[1] = rw * xv.y + (1.f - rw) * (c0.y + c1.y);
    o[2] = rw * xv.z + (1.f - rw) * (c0.z + c1.z);
    o[3] = rw * xv.w + (1.f - rw) * (c0.w + c1.w);

    float sm1 = o[0] + o[1] + o[2] + o[3];
    float sq  = o[0]*o[0] + o[1]*o[1] + o[2]*o[2] + o[3]*o[3];
    #pragma unroll
    for (int off = 32; off > 0; off >>= 1) { sm1 += __shfl_xor(sm1, off); sq += __shfl_xor(sq, off); }
    if (lane == 0) { rs[wid] = sm1; rq[wid] = sq; }
    __syncthreads();
    sm1 = rs[0] + rs[1] + rs[2] + rs[3];
    sq  = rq[0] + rq[1] + rq[2] + rq[3];
    float mu  = sm1 * (1.f/1024.f);
    float var = sq * (1.f/1024.f) - mu*mu;
    float inv = rsqrtf(var + 1e-5f);

    float4 lw = ((const float4*)p.lnw)[tid];
    float4 lb = ((const float4*)p.lnb)[tid];
    float4 y;
    y.x = (o[0] - mu)*inv*lw.x + lb.x;
    y.y = (o[1] - mu)*inv*lw.y + lb.y;
    y.z = (o[2] - mu)*inv*lw.z + lb.z;
    y.w = (o[3] - mu)*inv*lw.w + lb.w;
    ((float4*)(p.out + row*Dd))[tid] = y;
}

extern "C" void kernel_launch(void* const* d_in, const int* in_sizes, int n_in,
                              void* d_out, int out_size, void* d_ws, size_t ws_size,
                              hipStream_t stream)
{
    Params prm;
    prm.X     = (const float*)d_in[0];
    prm.posW  = (const float*)d_in[1];
    prm.posB  = (const float*)d_in[2];
    prm.pbias = (const float*)d_in[3];
    prm.spos  = (const float*)d_in[4];
    prm.lsc   = (const float*)d_in[5];
    prm.qW    = (const float*)d_in[6];
    prm.kW    = (const float*)d_in[7];
    prm.vW    = (const float*)d_in[8];
    prm.gates = (const float*)d_in[9];
    prm.rwp   = (const float*)d_in[10];
    prm.lnw   = (const float*)d_in[11];
    prm.lnb   = (const float*)d_in[12];

    char* ws = (char*)d_ws;
    size_t off = 0;
    prm.Xb  = (bf16*)(ws + off);   off += (size_t)Bb*Ss*Dd*2;
    prm.Wt  = (bf16*)(ws + off);   off += (size_t)3*Dd*Dd*2;
    prm.WpT = (bf16*)(ws + off);   off += (size_t)Ee*Dd*2;
    prm.QKV = (bf16*)(ws + off);   off += (size_t)2*2048*1024*2;  // Q,K only (V -> Vt)
    prm.Vt  = (bf16*)(ws + off);   off += (size_t)Bb*Dd*Ss*2;
    prm.Aav = (bf16*)(ws + off);   off += (size_t)Bb*Ss*Ss*2;
    prm.wh  = (__half*)(ws + off); off += (size_t)Bb*Ss*Nn*2;
    prm.qk0 = (float*)(ws + off);  off += (size_t)Bb*Ss*Ss*4;
    prm.qk1 = (float*)(ws + off);  off += (size_t)Bb*Ss*Ss*4;
    prm.cb0 = (float*)(ws + off);  off += (size_t)Bb*Ss*Dd*4;
    prm.cb1 = (float*)(ws + off);  off += (size_t)Bb*Ss*Dd*4;
    prm.out = (float*)d_out;
    (void)ws_size;

    k_prep    <<<dim3(16,16,4), 256, 0, stream>>>(prm);
    k_qkv_pos <<<416,            256, 0, stream>>>(prm);
    k_qkt     <<<288,            256, 0, stream>>>(prm);
    k_softmax <<<dim3(256, 2),   256, 0, stream>>>(prm);
    k_av      <<<384,            256, 0, stream>>>(prm);
    k_epilogue<<<2048,           256, 0, stream>>>(prm);
}

// Round 16
// 163.624 us; speedup vs baseline: 1.1160x; 1.0062x over previous
//
#include <hip/hip_runtime.h>
#include <hip/hip_bf16.h>
#include <hip/hip_fp16.h>

using bf16 = __hip_bfloat16;
typedef __attribute__((ext_vector_type(8))) short short8;
typedef __attribute__((ext_vector_type(4))) float f32x4;

static constexpr int Bb = 2, Ss = 1024, Dd = 1024, Ee = 64, Nn = 16;

struct Params {
    const float *X, *posW, *posB, *pbias, *spos, *lsc, *qW, *kW, *vW, *gates, *rwp, *lnw, *lnb;
    bf16 *Xb, *Wt, *WpT, *QKV, *Vt, *Aav;
    __half *wh;
    float *qk[4], *cb[4], *out;
};

__device__ __forceinline__ unsigned short f2bfr(float f) {
    __hip_bfloat16 h = __float2bfloat16(f);
    return *reinterpret_cast<unsigned short*>(&h);
}

#define GL_LDS(gp, lp) __builtin_amdgcn_global_load_lds( \
    (const __attribute__((address_space(1))) void*)(gp), \
    (__attribute__((address_space(3))) void*)(lp), 16, 0, 0)

// ---------- f32 -> bf16 transpose of a 64x64 tile ----------
__device__ __forceinline__ void do_transpose_f2b(
    const float* __restrict__ in, bf16* __restrict__ out,
    int R, int C, int bx, int by, char* sm)
{
    float (*tile)[65] = (float(*)[65])sm;
    int tx = threadIdx.x & 63, ty = threadIdx.x >> 6;
    int r0 = by * 64, c0 = bx * 64;
    #pragma unroll
    for (int i = 0; i < 16; ++i)
        tile[ty + i*4][tx] = in[(long)(r0 + ty + i*4)*C + c0 + tx];
    __syncthreads();
    #pragma unroll
    for (int i = 0; i < 16; ++i)
        out[(long)(c0 + ty + i*4)*R + r0 + tx] = __float2bfloat16(tile[tx][ty + i*4]);
    __syncthreads();
}

// ---------- 64x128 MFMA GEMM tile, BK=64, XOR-swizzled (R7-proven; qk/AV) ----------
__device__ __forceinline__ void do_gemm64(
    const bf16* __restrict__ Ab, const bf16* __restrict__ Bw, float* __restrict__ C,
    int Nc, int m0, int n0, int kBeg, int kEnd, float scale, char* sm)
{
    short* lA = (short*)sm;            // 8 KB
    short* lB = (short*)(sm + 8192);   // 16 KB
    int tid = threadIdx.x, wid = tid >> 6, lane = tid & 63;
    int wn = wid * 32, r16 = lane & 15, quad = lane >> 4;

    f32x4 acc[4][2];
    #pragma unroll
    for (int i = 0; i < 4; ++i)
        #pragma unroll
        for (int j = 0; j < 2; ++j)
            #pragma unroll
            for (int c = 0; c < 4; ++c) acc[i][j][c] = 0.f;

    const short* Ag = (const short*)Ab;
    const short* Bg = (const short*)Bw;

    int arow[2], akg[2], brow[4], bkg[4];
    #pragma unroll
    for (int j = 0; j < 2; ++j) {
        int c = tid + j*256; arow[j] = c >> 3; akg[j] = (c & 7) ^ (arow[j] & 7);
    }
    #pragma unroll
    for (int j = 0; j < 4; ++j) {
        int c = tid + j*256; brow[j] = c >> 3; bkg[j] = (c & 7) ^ (brow[j] & 7);
    }

    for (int k0 = kBeg; k0 < kEnd; k0 += 64) {
        __syncthreads();
        #pragma unroll
        for (int j = 0; j < 2; ++j)
            GL_LDS(Ag + (long)(m0 + arow[j])*1024 + k0 + akg[j]*8, lA + (tid + j*256)*8);
        #pragma unroll
        for (int j = 0; j < 4; ++j)
            GL_LDS(Bg + (long)(n0 + brow[j])*1024 + k0 + bkg[j]*8, lB + (tid + j*256)*8);
        __syncthreads();

        #pragma unroll
        for (int kk = 0; kk < 2; ++kk) {
            int kc = kk*4 + quad;
            short8 af[4], bfv[2];
            #pragma unroll
            for (int i = 0; i < 4; ++i) {
                int r = i*16 + r16;
                af[i] = *(const short8*)(lA + r*64 + (kc ^ (r & 7))*8);
            }
            #pragma unroll
            for (int j = 0; j < 2; ++j) {
                int r = wn + j*16 + r16;
                bfv[j] = *(const short8*)(lB + r*64 + (kc ^ (r & 7))*8);
            }
            #pragma unroll
            for (int i = 0; i < 4; ++i)
                #pragma unroll
                for (int j = 0; j < 2; ++j)
                    acc[i][j] = __builtin_amdgcn_mfma_f32_16x16x32_bf16(af[i], bfv[j], acc[i][j], 0, 0, 0);
        }
    }

    #pragma unroll
    for (int i = 0; i < 4; ++i)
        #pragma unroll
        for (int j = 0; j < 2; ++j)
            #pragma unroll
            for (int rr = 0; rr < 4; ++rr)
                C[(long)(m0 + i*16 + quad*4 + rr)*Nc + n0 + wn + j*16 + r16] =
                    acc[i][j][rr] * scale;
}

// ---------- 128x128 MFMA GEMM tile (m97 structure), BK=64, XOR-swizzled ----------
template<int OUT_MODE>
__device__ __forceinline__ void do_gemm128(
    const bf16* __restrict__ Ab, const bf16* __restrict__ Bw, void* __restrict__ Cv,
    int Nc, int m0, int n0, char* sm)
{
    short* lA = (short*)sm;             // 16 KB
    short* lB = (short*)(sm + 16384);   // 16 KB
    int tid = threadIdx.x, wid = tid >> 6, lane = tid & 63;
    int wm = (wid >> 1) * 64, wnn = (wid & 1) * 64;
    int r16 = lane & 15, quad = lane >> 4;

    f32x4 acc[4][4];
    #pragma unroll
    for (int i = 0; i < 4; ++i)
        #pragma unroll
        for (int j = 0; j < 4; ++j)
            #pragma unroll
            for (int c = 0; c < 4; ++c) acc[i][j][c] = 0.f;

    const short* Ag = (const short*)Ab;
    const short* Bg = (const short*)Bw;

    int rowc[4], kgc[4];
    #pragma unroll
    for (int j = 0; j < 4; ++j) {
        int c = tid + j*256; rowc[j] = c >> 3; kgc[j] = (c & 7) ^ (rowc[j] & 7);
    }

    for (int k0 = 0; k0 < 1024; k0 += 64) {
        __syncthreads();
        #pragma unroll
        for (int j = 0; j < 4; ++j)
            GL_LDS(Ag + (long)(m0 + rowc[j])*1024 + k0 + kgc[j]*8, lA + (tid + j*256)*8);
        #pragma unroll
        for (int j = 0; j < 4; ++j)
            GL_LDS(Bg + (long)(n0 + rowc[j])*1024 + k0 + kgc[j]*8, lB + (tid + j*256)*8);
        __syncthreads();

        #pragma unroll
        for (int kk = 0; kk < 2; ++kk) {
            int kc = kk*4 + quad;
            short8 af[4], bfv[4];
            #pragma unroll
            for (int i = 0; i < 4; ++i) {
                int r = wm + i*16 + r16;
                af[i] = *(const short8*)(lA + r*64 + (kc ^ (r & 7))*8);
            }
            #pragma unroll
            for (int j = 0; j < 4; ++j) {
                int r = wnn + j*16 + r16;
                bfv[j] = *(const short8*)(lB + r*64 + (kc ^ (r & 7))*8);
            }
            #pragma unroll
            for (int i = 0; i < 4; ++i)
                #pragma unroll
                for (int j = 0; j < 4; ++j)
                    acc[i][j] = __builtin_amdgcn_mfma_f32_16x16x32_bf16(af[i], bfv[j], acc[i][j], 0, 0, 0);
        }
    }

    if (OUT_MODE == 1) {
        bf16* C = (bf16*)Cv;
        #pragma unroll
        for (int i = 0; i < 4; ++i)
            #pragma unroll
            for (int j = 0; j < 4; ++j)
                #pragma unroll
                for (int rr = 0; rr < 4; ++rr)
                    C[(long)(m0 + wm + i*16 + quad*4 + rr)*Nc + n0 + wnn + j*16 + r16] =
                        __float2bfloat16(acc[i][j][rr]);
    } else {
        __syncthreads();
        bf16 (*lt)[132] = (bf16(*)[132])sm;   // 33792 B
        #pragma unroll
        for (int i = 0; i < 4; ++i)
            #pragma unroll
            for (int j = 0; j < 4; ++j)
                #pragma unroll
                for (int rr = 0; rr < 4; ++rr)
                    lt[wnn + j*16 + r16][wm + i*16 + quad*4 + rr] =
                        __float2bfloat16(acc[i][j][rr]);
        __syncthreads();
        bf16* Vb = (bf16*)Cv + (long)(m0 >> 10) * Dd * Ss;
        int s0 = m0 & (Ss - 1);
        int colBase = wid * 32 + (lane >> 4);
        int idx = (lane & 15) * 8;
        #pragma unroll
        for (int it = 0; it < 8; ++it) {
            int col = colBase + it * 4;
            ushort4 v0 = *(const ushort4*)&lt[col][idx];
            ushort4 v1 = *(const ushort4*)&lt[col][idx + 4];
            *(ushort4*)(Vb + (long)(n0 + col)*Ss + s0 + idx)     = v0;
            *(ushort4*)(Vb + (long)(n0 + col)*Ss + s0 + idx + 4) = v1;
        }
    }
}

// ---------- pos GEMM (64 rows) + tanh/bias + splat influence -> wh (half) ----------
__device__ __forceinline__ void do_pos(const Params& p, int m0, char* sm)
{
    short* lA = (short*)sm;
    short* lB = (short*)(sm + 4096);
    float (*P)[65]  = (float(*)[65])(sm + 8192);
    float (*sp)[65] = (float(*)[65])(sm + 8192 + 64*65*4);

    int tid = threadIdx.x, wid = tid >> 6, lane = tid & 63;
    int r16 = lane & 15, quad = lane >> 4;

    for (int idx = tid; idx < 16*64; idx += 256)
        sp[idx >> 6][idx & 63] = p.spos[idx];

    f32x4 acc[4];
    #pragma unroll
    for (int j = 0; j < 4; ++j)
        #pragma unroll
        for (int c = 0; c < 4; ++c) acc[j][c] = 0.f;

    int ra = tid >> 2, ka = (tid & 3) * 8;
    const short* Ag = (const short*)p.Xb;
    const short* Bg = (const short*)p.WpT;

    for (int k0 = 0; k0 < Dd; k0 += 32) {
        __syncthreads();
        GL_LDS(Ag + (long)(m0+ra)*1024 + k0 + ka, lA + tid*8);
        GL_LDS(Bg + (long)ra*1024 + k0 + ka,      lB + tid*8);
        __syncthreads();

        short8 af = *(const short8*)(lA + (wid*16 + r16)*32 + quad*8);
        #pragma unroll
        for (int j = 0; j < 4; ++j) {
            short8 bfv = *(const short8*)(lB + (j*16 + r16)*32 + quad*8);
            acc[j] = __builtin_amdgcn_mfma_f32_16x16x32_bf16(af, bfv, acc[j], 0, 0, 0);
        }
    }

    #pragma unroll
    for (int j = 0; j < 4; ++j)
        #pragma unroll
        for (int rr = 0; rr < 4; ++rr) {
            int rl  = wid*16 + quad*4 + rr;
            int col = j*16 + r16;
            int srow = (m0 + rl) & (Ss - 1);
            P[rl][col] = tanhf(acc[j][rr] + p.posB[col]) + p.pbias[srow*Ee + col];
        }
    __syncthreads();

    int n  = tid & 15;
    int rb = (tid >> 4) * 4;
    float sc = __expf(p.lsc[n]);
    sc = fminf(fmaxf(sc, 0.3f), 2.0f);
    float inv2 = -0.5f / (sc * sc);
    #pragma unroll
    for (int rr = 0; rr < 4; ++rr) {
        int row = rb + rr;
        float d2 = 0.f;
        #pragma unroll 16
        for (int e = 0; e < 64; ++e) {
            float df = P[row][e] - sp[n][e];
            d2 += df * df;
        }
        float infl = fmaxf(__expf(d2 * inv2), 0.01f);
        p.wh[(long)(m0 + row)*Nn + n] = __float2half(infl);
    }
}

// ========== K1: weight transposes + posW^T + X cast ==========
__global__ __launch_bounds__(256) void k_prep(Params p)
{
    __shared__ __align__(16) char sm[64*65*4];
    int z = blockIdx.z;
    if (z < 3) {
        const float* w = (z == 0) ? p.qW : (z == 1) ? p.kW : p.vW;
        do_transpose_f2b(w, p.Wt + (long)z*Dd*Dd, Dd, Dd, blockIdx.x, blockIdx.y, sm);
    } else if (blockIdx.x == 0) {
        do_transpose_f2b(p.posW, p.WpT, Dd, Ee, 0, blockIdx.y, sm);
    } else {
        int job = blockIdx.y * 15 + (blockIdx.x - 1);     // 0..239
        const float4* src = (const float4*)p.X;
        ushort4* dst = (ushort4*)p.Xb;
        for (int idx = job*256 + (int)threadIdx.x; idx < Bb*Ss*Dd/4; idx += 240*256) {
            float4 v = src[idx];
            ushort4 y;
            y.x = f2bfr(v.x); y.y = f2bfr(v.y); y.z = f2bfr(v.z); y.w = f2bfr(v.w);
            dst[idx] = y;
        }
    }
}

// ========== K2: QKV GEMM 128x128 (384 jobs; V transposed) + pos (32 jobs) ==========
__global__ __launch_bounds__(256) void k_qkv_pos(Params p)
{
    __shared__ __align__(16) char sm[33792];
    int job = blockIdx.x;
    if (job < 384) {
        int z = job >> 7, t = job & 127;
        int bm = t >> 3, bn = t & 7;
        if (z < 2)
            do_gemm128<1>(p.Xb, p.Wt + (long)z*Dd*Dd, p.QKV + (long)z*2048*1024,
                          Dd, bm*128, bn*128, sm);
        else
            do_gemm128<2>(p.Xb, p.Wt + (long)2*Dd*Dd, p.Vt,
                          Dd, bm*128, bn*128, sm);
    } else {
        do_pos(p, (job - 384)*64, sm);
    }
}

// ========== K3: qk split-K=4 (576 jobs) ==========
__global__ __launch_bounds__(256) void k_qkt(Params p)
{
    __shared__ __align__(16) char sm[24576];
    int job = blockIdx.x;
    int h = job & 3, pairIdx = job >> 2;
    int b = pairIdx / 72, t = pairIdx % 72;
    int acc = 0, bm = 0, bn = 0;
    #pragma unroll
    for (int u = 0; u < 16; ++u) {
        int c = (u >> 1) + 1;
        if (t < acc + c) { bm = u; bn = t - acc; break; }
        acc += c;
    }
    const bf16* Qb = p.QKV + (long)b*Ss*Dd;
    const bf16* Kb = p.QKV + (long)2048*1024 + (long)b*Ss*Dd;
    float* dst = p.qk[h] + (long)b*Ss*Ss;
    do_gemm64(Qb, Kb, dst, Ss, bm*64, bn*128, h*256, h*256 + 256, 0.03125f, sm);
}

// ========== K4: softmax + gated average over 4 qk partials ==========
__global__ __launch_bounds__(256) void k_softmax(Params p)
{
    __shared__ __align__(16) char sm[36864 + 256];
    __half2 (*wt)[9] = (__half2(*)[9])sm;
    float (*wi4)[16] = (float(*)[16])(sm + 36864);

    int base = blockIdx.x * 4, b = blockIdx.y;
    int tid = threadIdx.x, wid = tid >> 6, lane = tid & 63;
    int imax = base + 3;

    const __half*  whb  = p.wh + (long)b*Ss*Nn;
    const __half2* whb2 = (const __half2*)whb;

    for (int j = tid; j <= imax; j += 256) {
        #pragma unroll
        for (int h = 0; h < 8; ++h)
            wt[j][h] = whb2[j*8 + h];
    }
    if (tid < 64) wi4[tid >> 4][tid & 15] =
        __half2float(whb[(long)(base + (tid >> 4))*16 + (tid & 15)]);
    __syncthreads();

    int i = base + wid;
    long roff = ((long)b*Ss + i)*Ss;
    const float* q0 = p.qk[0] + roff;
    const float* q1 = p.qk[1] + roff;
    const float* q2 = p.qk[2] + roff;
    const float* q3 = p.qk[3] + roff;
    bf16* arow      = p.Aav + roff;

    float wiR[16], l[16];
    #pragma unroll
    for (int n = 0; n < 16; ++n) { wiR[n] = wi4[wid][n]; l[n] = 0.f; }

    for (int j = lane; j <= i; j += 64) {
        float q = (q0[j] + q1[j]) + (q2[j] + q3[j]);
        #pragma unroll
        for (int h = 0; h < 8; ++h) {
            float2 f = __half22float2(wt[j][h]);
            l[2*h]     += __expf(wiR[2*h]     * f.x * q);
            l[2*h + 1] += __expf(wiR[2*h + 1] * f.y * q);
        }
    }
    #pragma unroll
    for (int n = 0; n < 16; ++n)
        #pragma unroll
        for (int off = 32; off > 0; off >>= 1)
            l[n] += __shfl_xor(l[n], off);

    float coef[16];
    #pragma unroll
    for (int n = 0; n < 16; ++n) {
        float g  = p.gates[n];
        float sg = 1.f / (1.f + __expf(-g));
        coef[n]  = sg / (16.f * l[n]);
    }

    for (int j = lane; j < Ss; j += 64) {
        float a = 0.f;
        if (j <= i) {
            float q = (q0[j] + q1[j]) + (q2[j] + q3[j]);
            #pragma unroll
            for (int h = 0; h < 8; ++h) {
                float2 f = __half22float2(wt[j][h]);
                a += coef[2*h]     * __expf(wiR[2*h]     * f.x * q);
                a += coef[2*h + 1] * __expf(wiR[2*h + 1] * f.y * q);
            }
        }
        arow[j] = __float2bfloat16(a);
    }
}

// ========== K5: AV GEMM split-K<=4 (640 jobs) ==========
// K-range for row-block bm is [0,(bm+1)*64); chunks of 256 -> nch = (bm>>2)+1.
__global__ __launch_bounds__(256) void k_av(Params p)
{
    __shared__ __align__(16) char sm[24576];
    int job = blockIdx.x;
    int b  = job / 320;
    int r  = job % 320;
    int bn = r / 40;
    int u  = r % 40;
    int acc = 0, bm = 0, h = 0;
    #pragma unroll
    for (int m = 0; m < 16; ++m) {
        int c = (m >> 2) + 1;
        if (u < acc + c) { bm = m; h = u - acc; break; }
        acc += c;
    }
    int kBeg = h * 256;
    int kEnd = (bm + 1) * 64; if (kEnd > kBeg + 256) kEnd = kBeg + 256;

    const bf16* Ab = p.Aav + (long)b*Ss*Ss;
    const bf16* Bw = p.Vt + (long)b*Dd*Ss;
    float* dst = p.cb[h] + (long)b*Ss*Dd;
    do_gemm64(Ab, Bw, dst, Dd, bm*64, bn*128, kBeg, kEnd, 1.f, sm);
}

// ========== K6: residual + LayerNorm over 4 cb partials ==========
__global__ __launch_bounds__(256) void k_epilogue(Params p)
{
    __shared__ float rs[4], rq[4];
    long row = blockIdx.x;
    int tid = threadIdx.x, wid = tid >> 6, lane = tid & 63;
    float rw = 1.f / (1.f + __expf(-p.rwp[0]));

    int s = (int)(row & (Ss - 1));
    float4 c = ((const float4*)(p.cb[0] + row*Dd))[tid];
    #pragma unroll
    for (int h = 1; h < 4; ++h) {
        if (s >= h*256) {
            float4 ch = ((const float4*)(p.cb[h] + row*Dd))[tid];
            c.x += ch.x; c.y += ch.y; c.z += ch.z; c.w += ch.w;
        }
    }
    float4 xv = ((const float4*)(p.X + row*Dd))[tid];

    float o[4];
    o[0] = rw * xv.x + (1.f - rw) * c.x;
    o[1] = rw * xv.y + (1.f - rw) * c.y;
    o[2] = rw * xv.z + (1.f - rw) * c.z;
    o[3] = rw * xv.w + (1.f - rw) * c.w;

    float sm1 = o[0] + o[1] + o[2] + o[3];
    float sq  = o[0]*o[0] + o[1]*o[1] + o[2]*o[2] + o[3]*o[3];
    #pragma unroll
    for (int off = 32; off > 0; off >>= 1) { sm1 += __shfl_xor(sm1, off); sq += __shfl_xor(sq, off); }
    if (lane == 0) { rs[wid] = sm1; rq[wid] = sq; }
    __syncthreads();
    sm1 = rs[0] + rs[1] + rs[2] + rs[3];
    sq  = rq[0] + rq[1] + rq[2] + rq[3];
    float mu  = sm1 * (1.f/1024.f);
    float var = sq * (1.f/1024.f) - mu*mu;
    float inv = rsqrtf(var + 1e-5f);

    float4 lw = ((const float4*)p.lnw)[tid];
    float4 lb = ((const float4*)p.lnb)[tid];
    float4 y;
    y.x = (o[0] - mu)*inv*lw.x + lb.x;
    y.y = (o[1] - mu)*inv*lw.y + lb.y;
    y.z = (o[2] - mu)*inv*lw.z + lb.z;
    y.w = (o[3] - mu)*inv*lw.w + lb.w;
    ((float4*)(p.out + row*Dd))[tid] = y;
}

extern "C" void kernel_launch(void* const* d_in, const int* in_sizes, int n_in,
                              void* d_out, int out_size, void* d_ws, size_t ws_size,
                              hipStream_t stream)
{
    Params prm;
    prm.X     = (const float*)d_in[0];
    prm.posW  = (const float*)d_in[1];
    prm.posB  = (const float*)d_in[2];
    prm.pbias = (const float*)d_in[3];
    prm.spos  = (const float*)d_in[4];
    prm.lsc   = (const float*)d_in[5];
    prm.qW    = (const float*)d_in[6];
    prm.kW    = (const float*)d_in[7];
    prm.vW    = (const float*)d_in[8];
    prm.gates = (const float*)d_in[9];
    prm.rwp   = (const float*)d_in[10];
    prm.lnw   = (const float*)d_in[11];
    prm.lnb   = (const float*)d_in[12];

    char* ws = (char*)d_ws;
    size_t off = 0;
    prm.Xb  = (bf16*)(ws + off);   off += (size_t)Bb*Ss*Dd*2;
    prm.Wt  = (bf16*)(ws + off);   off += (size_t)3*Dd*Dd*2;
    prm.WpT = (bf16*)(ws + off);   off += (size_t)Ee*Dd*2;
    prm.QKV = (bf16*)(ws + off);   off += (size_t)2*2048*1024*2;  // Q,K only (V -> Vt)
    prm.Vt  = (bf16*)(ws + off);   off += (size_t)Bb*Dd*Ss*2;
    prm.Aav = (bf16*)(ws + off);   off += (size_t)Bb*Ss*Ss*2;
    prm.wh  = (__half*)(ws + off); off += (size_t)Bb*Ss*Nn*2;
    for (int h = 0; h < 4; ++h) { prm.qk[h] = (float*)(ws + off); off += (size_t)Bb*Ss*Ss*4; }
    for (int h = 0; h < 4; ++h) { prm.cb[h] = (float*)(ws + off); off += (size_t)Bb*Ss*Dd*4; }
    prm.out = (float*)d_out;
    (void)ws_size;

    k_prep    <<<dim3(16,16,4), 256, 0, stream>>>(prm);
    k_qkv_pos <<<416,            256, 0, stream>>>(prm);
    k_qkt     <<<576,            256, 0, stream>>>(prm);
    k_softmax <<<dim3(256, 2),   256, 0, stream>>>(prm);
    k_av      <<<640,            256, 0, stream>>>(prm);
    k_epilogue<<<2048,           256, 0, stream>>>(prm);
}